// Round 1
// baseline (990.980 us; speedup 1.0000x reference)
//
#include <hip/hip_runtime.h>
#include <hip/hip_bf16.h>

#define B_ 2
#define T_ 2048
#define C_ 1024
#define NH_ 16
#define HD_ 64

using bf16 = __hip_bfloat16;

__device__ __forceinline__ float bf2f(unsigned short u) {
    union { unsigned int i; float f; } v;
    v.i = ((unsigned int)u) << 16;
    return v.f;
}
__device__ __forceinline__ unsigned short f2bf(float f) {
    union { float f; unsigned int u; } v;
    v.f = f;
    unsigned int r = v.u + 0x7fffu + ((v.u >> 16) & 1u);  // RNE
    return (unsigned short)(r >> 16);
}

// ---------------------------------------------------------------------------
// Kernel 1: QKV GEMM.  X[4096,1024] @ W[1024,3072] -> Q/K/V bf16 [B*NH][T][HD]
// 128x128 tile, TK=16, 256 threads, 8x8 micro-tile, fp32 accumulate.
// ---------------------------------------------------------------------------
__global__ __launch_bounds__(256) void qkv_gemm(
    const float* __restrict__ X, const float* __restrict__ W,
    bf16* __restrict__ Qb, bf16* __restrict__ Kb, bf16* __restrict__ Vb) {
    __shared__ float As[16][128];   // transposed: As[k][m]
    __shared__ float Bs[16][128];
    const int t  = threadIdx.x;
    const int m0 = blockIdx.y * 128;
    const int n0 = blockIdx.x * 128;
    const int a_id = t & 15;        // output row group (8 rows)
    const int b_id = t >> 4;        // output col group (8 cols)
    const int lrow = t >> 1, lk = (t & 1) * 8;        // A load: row, k-offset
    const int brow = t >> 4, bcol = (t & 15) * 8;     // B load
    float acc[8][8] = {};

    for (int k0 = 0; k0 < C_; k0 += 16) {
        __syncthreads();
        float4 a0 = *reinterpret_cast<const float4*>(&X[(size_t)(m0 + lrow) * C_ + k0 + lk]);
        float4 a1 = *reinterpret_cast<const float4*>(&X[(size_t)(m0 + lrow) * C_ + k0 + lk + 4]);
        As[lk + 0][lrow] = a0.x; As[lk + 1][lrow] = a0.y;
        As[lk + 2][lrow] = a0.z; As[lk + 3][lrow] = a0.w;
        As[lk + 4][lrow] = a1.x; As[lk + 5][lrow] = a1.y;
        As[lk + 6][lrow] = a1.z; As[lk + 7][lrow] = a1.w;
        *reinterpret_cast<float4*>(&Bs[brow][bcol]) =
            *reinterpret_cast<const float4*>(&W[(size_t)(k0 + brow) * (3 * C_) + n0 + bcol]);
        *reinterpret_cast<float4*>(&Bs[brow][bcol + 4]) =
            *reinterpret_cast<const float4*>(&W[(size_t)(k0 + brow) * (3 * C_) + n0 + bcol + 4]);
        __syncthreads();
        #pragma unroll
        for (int k = 0; k < 16; ++k) {
            float a[8], bfr[8];
            *reinterpret_cast<float4*>(&a[0])   = *reinterpret_cast<const float4*>(&As[k][a_id * 8]);
            *reinterpret_cast<float4*>(&a[4])   = *reinterpret_cast<const float4*>(&As[k][a_id * 8 + 4]);
            *reinterpret_cast<float4*>(&bfr[0]) = *reinterpret_cast<const float4*>(&Bs[k][b_id * 8]);
            *reinterpret_cast<float4*>(&bfr[4]) = *reinterpret_cast<const float4*>(&Bs[k][b_id * 8 + 4]);
            #pragma unroll
            for (int i = 0; i < 8; ++i)
                #pragma unroll
                for (int j = 0; j < 8; ++j)
                    acc[i][j] += a[i] * bfr[j];
        }
    }

    // Epilogue: scatter into head-major Q/K/V (thread's 8 cols stay in one head)
    const int nbase = n0 + b_id * 8;
    const int which = nbase >> 10;          // 0=Q 1=K 2=V
    const int h     = (nbase >> 6) & (NH_ - 1);
    const int dbase = nbase & (HD_ - 1);
    bf16* dst = (which == 0) ? Qb : ((which == 1) ? Kb : Vb);
    #pragma unroll
    for (int i = 0; i < 8; ++i) {
        int m  = m0 + a_id * 8 + i;
        int bb = m >> 11;                   // m / T_
        int tq = m & (T_ - 1);
        bf16* p = dst + ((size_t)((bb << 4) | h) * T_ + tq) * HD_ + dbase;
        union { unsigned short s[4]; uint2 u; } w0, w1;
        #pragma unroll
        for (int j = 0; j < 4; ++j) { w0.s[j] = f2bf(acc[i][j]); w1.s[j] = f2bf(acc[i][j + 4]); }
        *reinterpret_cast<uint2*>(p)     = w0.u;
        *reinterpret_cast<uint2*>(p + 4) = w1.u;
    }
}

// ---------------------------------------------------------------------------
// Kernel 2: causal flash attention. Block = (head, 64 q-rows), 256 threads.
// fp32 compute, online softmax, K transposed in LDS, P staged as bf16.
// ---------------------------------------------------------------------------
__global__ __launch_bounds__(256) void attn(
    const bf16* __restrict__ Qb, const bf16* __restrict__ Kb,
    const bf16* __restrict__ Vb, bf16* __restrict__ Yb) {
    __shared__ float Qs[64][68];            // [q][d], pre-scaled by 1/8
    __shared__ float Kt[64][68];            // transposed: Kt[d][j]
    __shared__ float Vs[64][64];            // [j][d]
    __shared__ unsigned short Pb[64][72];   // bf16 P[q][j]

    const int t  = threadIdx.x;
    const int qt = blockIdx.x;              // q-tile 0..31
    const int bh = blockIdx.y;              // b*NH + h
    const int q0 = qt * 64;
    const bf16* Qh = Qb + (size_t)bh * T_ * HD_;
    const bf16* Kh = Kb + (size_t)bh * T_ * HD_;
    const bf16* Vh = Vb + (size_t)bh * T_ * HD_;

    const int lrow = t >> 2, lcol = (t & 3) * 16;   // tile loads: 16 bf16/thread

    {   // load Q tile (scale folded in)
        union { uint4 v[2]; unsigned short s[16]; } u;
        u.v[0] = *reinterpret_cast<const uint4*>(&Qh[(size_t)(q0 + lrow) * HD_ + lcol]);
        u.v[1] = *reinterpret_cast<const uint4*>(&Qh[(size_t)(q0 + lrow) * HD_ + lcol + 8]);
        #pragma unroll
        for (int j = 0; j < 16; ++j) Qs[lrow][lcol + j] = bf2f(u.s[j]) * 0.125f;
    }

    const int r_id = t >> 4;   // row group: rows r_id*4..+3
    const int c_id = t & 15;   // col group: cols c_id*4..+3
    float m_run[4], l_run[4], y[4][4];
    #pragma unroll
    for (int i = 0; i < 4; ++i) {
        m_run[i] = -1e30f; l_run[i] = 0.f;
        #pragma unroll
        for (int d = 0; d < 4; ++d) y[i][d] = 0.f;
    }

    const int nt = qt + 1;
    for (int kt = 0; kt < nt; ++kt) {
        __syncthreads();                    // protect Kt/Vs/Pb from prev PV
        const int j0 = kt * 64;
        {   // load K (transposed) and V
            union { uint4 v[2]; unsigned short s[16]; } uk, uv;
            uk.v[0] = *reinterpret_cast<const uint4*>(&Kh[(size_t)(j0 + lrow) * HD_ + lcol]);
            uk.v[1] = *reinterpret_cast<const uint4*>(&Kh[(size_t)(j0 + lrow) * HD_ + lcol + 8]);
            uv.v[0] = *reinterpret_cast<const uint4*>(&Vh[(size_t)(j0 + lrow) * HD_ + lcol]);
            uv.v[1] = *reinterpret_cast<const uint4*>(&Vh[(size_t)(j0 + lrow) * HD_ + lcol + 8]);
            #pragma unroll
            for (int j = 0; j < 16; ++j) Kt[lcol + j][lrow] = bf2f(uk.s[j]);
            #pragma unroll
            for (int j4 = 0; j4 < 4; ++j4) {
                float4 vv;
                vv.x = bf2f(uv.s[j4 * 4 + 0]); vv.y = bf2f(uv.s[j4 * 4 + 1]);
                vv.z = bf2f(uv.s[j4 * 4 + 2]); vv.w = bf2f(uv.s[j4 * 4 + 3]);
                *reinterpret_cast<float4*>(&Vs[lrow][lcol + j4 * 4]) = vv;
            }
        }
        __syncthreads();

        // S = (Q/8) K^T   4x4 per thread
        float s[4][4] = {};
        #pragma unroll
        for (int d4 = 0; d4 < 16; ++d4) {
            float qa[4][4];
            #pragma unroll
            for (int ii = 0; ii < 4; ++ii)
                *reinterpret_cast<float4*>(qa[ii]) =
                    *reinterpret_cast<const float4*>(&Qs[r_id * 4 + ii][d4 * 4]);
            #pragma unroll
            for (int dd = 0; dd < 4; ++dd) {
                float ka[4];
                *reinterpret_cast<float4*>(ka) =
                    *reinterpret_cast<const float4*>(&Kt[d4 * 4 + dd][c_id * 4]);
                #pragma unroll
                for (int ii = 0; ii < 4; ++ii)
                    #pragma unroll
                    for (int jj = 0; jj < 4; ++jj)
                        s[ii][jj] += qa[ii][dd] * ka[jj];
            }
        }

        if (kt == qt) {                     // causal mask on diagonal tile
            #pragma unroll
            for (int ii = 0; ii < 4; ++ii)
                #pragma unroll
                for (int jj = 0; jj < 4; ++jj)
                    if (c_id * 4 + jj > r_id * 4 + ii) s[ii][jj] = -1e30f;
        }

        // online softmax (16 threads per row via shfl_xor over lane bits 0..3)
        #pragma unroll
        for (int ii = 0; ii < 4; ++ii) {
            float tmax = fmaxf(fmaxf(s[ii][0], s[ii][1]), fmaxf(s[ii][2], s[ii][3]));
            #pragma unroll
            for (int off = 1; off < 16; off <<= 1)
                tmax = fmaxf(tmax, __shfl_xor(tmax, off, 64));
            float mnew = fmaxf(m_run[ii], tmax);
            float sc   = __expf(m_run[ii] - mnew);
            float psum = 0.f;
            #pragma unroll
            for (int jj = 0; jj < 4; ++jj) {
                float p = __expf(s[ii][jj] - mnew);
                s[ii][jj] = p;
                psum += p;
            }
            #pragma unroll
            for (int off = 1; off < 16; off <<= 1)
                psum += __shfl_xor(psum, off, 64);
            l_run[ii] = l_run[ii] * sc + psum;
            m_run[ii] = mnew;
            #pragma unroll
            for (int dd = 0; dd < 4; ++dd) y[ii][dd] *= sc;
            union { unsigned short s4[4]; uint2 u; } pw;
            #pragma unroll
            for (int jj = 0; jj < 4; ++jj) pw.s4[jj] = f2bf(s[ii][jj]);
            *reinterpret_cast<uint2*>(&Pb[r_id * 4 + ii][c_id * 4]) = pw.u;
        }
        __syncthreads();

        // y += P V   4x4 per thread
        #pragma unroll
        for (int j4 = 0; j4 < 16; ++j4) {
            float pa[4][4];
            #pragma unroll
            for (int ii = 0; ii < 4; ++ii) {
                union { unsigned short s4[4]; uint2 u; } pr;
                pr.u = *reinterpret_cast<const uint2*>(&Pb[r_id * 4 + ii][j4 * 4]);
                #pragma unroll
                for (int jj = 0; jj < 4; ++jj) pa[ii][jj] = bf2f(pr.s4[jj]);
            }
            float va[4][4];
            #pragma unroll
            for (int jj = 0; jj < 4; ++jj)
                *reinterpret_cast<float4*>(va[jj]) =
                    *reinterpret_cast<const float4*>(&Vs[j4 * 4 + jj][c_id * 4]);
            #pragma unroll
            for (int ii = 0; ii < 4; ++ii)
                #pragma unroll
                for (int jj = 0; jj < 4; ++jj)
                    #pragma unroll
                    for (int dd = 0; dd < 4; ++dd)
                        y[ii][dd] += pa[ii][jj] * va[jj][dd];
        }
    }

    // epilogue: normalize, write Y bf16 [B*T][C] at column h*64+...
    const int bb = bh >> 4, h = bh & (NH_ - 1);
    #pragma unroll
    for (int ii = 0; ii < 4; ++ii) {
        float inv = 1.0f / l_run[ii];
        int grow = bb * T_ + q0 + r_id * 4 + ii;
        int col  = h * HD_ + c_id * 4;
        union { unsigned short s4[4]; uint2 u; } ow;
        #pragma unroll
        for (int dd = 0; dd < 4; ++dd) ow.s4[dd] = f2bf(y[ii][dd] * inv);
        *reinterpret_cast<uint2*>(&Yb[(size_t)grow * C_ + col]) = ow.u;
    }
}

// ---------------------------------------------------------------------------
// Kernel 3: projection GEMM. Y(bf16)[4096,1024] @ Wp(f32)[1024,1024] -> out f32
// ---------------------------------------------------------------------------
__global__ __launch_bounds__(256) void proj_gemm(
    const bf16* __restrict__ Yb, const float* __restrict__ W,
    float* __restrict__ Out) {
    __shared__ float As[16][128];
    __shared__ float Bs[16][128];
    const int t  = threadIdx.x;
    const int m0 = blockIdx.y * 128;
    const int n0 = blockIdx.x * 128;
    const int a_id = t & 15;
    const int b_id = t >> 4;
    const int lrow = t >> 1, lk = (t & 1) * 8;
    const int brow = t >> 4, bcol = (t & 15) * 8;
    float acc[8][8] = {};

    for (int k0 = 0; k0 < C_; k0 += 16) {
        __syncthreads();
        union { uint4 v; unsigned short s[8]; } ua;
        ua.v = *reinterpret_cast<const uint4*>(&Yb[(size_t)(m0 + lrow) * C_ + k0 + lk]);
        #pragma unroll
        for (int j = 0; j < 8; ++j) As[lk + j][lrow] = bf2f(ua.s[j]);
        *reinterpret_cast<float4*>(&Bs[brow][bcol]) =
            *reinterpret_cast<const float4*>(&W[(size_t)(k0 + brow) * C_ + n0 + bcol]);
        *reinterpret_cast<float4*>(&Bs[brow][bcol + 4]) =
            *reinterpret_cast<const float4*>(&W[(size_t)(k0 + brow) * C_ + n0 + bcol + 4]);
        __syncthreads();
        #pragma unroll
        for (int k = 0; k < 16; ++k) {
            float a[8], bfr[8];
            *reinterpret_cast<float4*>(&a[0])   = *reinterpret_cast<const float4*>(&As[k][a_id * 8]);
            *reinterpret_cast<float4*>(&a[4])   = *reinterpret_cast<const float4*>(&As[k][a_id * 8 + 4]);
            *reinterpret_cast<float4*>(&bfr[0]) = *reinterpret_cast<const float4*>(&Bs[k][b_id * 8]);
            *reinterpret_cast<float4*>(&bfr[4]) = *reinterpret_cast<const float4*>(&Bs[k][b_id * 8 + 4]);
            #pragma unroll
            for (int i = 0; i < 8; ++i)
                #pragma unroll
                for (int j = 0; j < 8; ++j)
                    acc[i][j] += a[i] * bfr[j];
        }
    }
    #pragma unroll
    for (int i = 0; i < 8; ++i) {
        int m = m0 + a_id * 8 + i;
        float* p = Out + (size_t)m * C_ + n0 + b_id * 8;
        *reinterpret_cast<float4*>(p)     = *reinterpret_cast<float4*>(&acc[i][0]);
        *reinterpret_cast<float4*>(p + 4) = *reinterpret_cast<float4*>(&acc[i][4]);
    }
}

extern "C" void kernel_launch(void* const* d_in, const int* in_sizes, int n_in,
                              void* d_out, int out_size, void* d_ws, size_t ws_size,
                              hipStream_t stream) {
    const float* x      = (const float*)d_in[0];
    const float* w_qkv  = (const float*)d_in[1];
    const float* w_proj = (const float*)d_in[2];
    float* out = (float*)d_out;

    const size_t HELEMS = (size_t)B_ * NH_ * T_ * HD_;   // 4,194,304
    bf16* Qb = (bf16*)d_ws;
    bf16* Kb = Qb + HELEMS;
    bf16* Vb = Kb + HELEMS;
    bf16* Yb = Vb + HELEMS;                               // total 32 MB

    qkv_gemm<<<dim3(24, 32), 256, 0, stream>>>(x, w_qkv, Qb, Kb, Vb);
    attn<<<dim3(32, 32), 256, 0, stream>>>(Qb, Kb, Vb, Yb);
    proj_gemm<<<dim3(8, 32), 256, 0, stream>>>(Yb, w_proj, out);
}

// Round 2
// 518.927 us; speedup vs baseline: 1.9097x; 1.9097x over previous
//
#include <hip/hip_runtime.h>
#include <hip/hip_bf16.h>

#define B_ 2
#define T_ 2048
#define C_ 1024
#define NH_ 16
#define HD_ 64

using bf16 = __hip_bfloat16;
typedef __attribute__((ext_vector_type(8))) short bf16x8;
typedef __attribute__((ext_vector_type(4))) float f32x4;

__device__ __forceinline__ float bf2f(unsigned short u) {
    union { unsigned int i; float f; } v;
    v.i = ((unsigned int)u) << 16;
    return v.f;
}
__device__ __forceinline__ unsigned short f2bf(float f) {
    union { float f; unsigned int u; } v;
    v.f = f;
    unsigned int r = v.u + 0x7fffu + ((v.u >> 16) & 1u);  // RNE
    return (unsigned short)(r >> 16);
}

// ---------------------------------------------------------------------------
// Kernel 1: QKV GEMM.  X[4096,1024] @ W[1024,3072] -> Q/K/V bf16 [B*NH][T][HD]
// (unchanged from round 0)
// ---------------------------------------------------------------------------
__global__ __launch_bounds__(256) void qkv_gemm(
    const float* __restrict__ X, const float* __restrict__ W,
    bf16* __restrict__ Qb, bf16* __restrict__ Kb, bf16* __restrict__ Vb) {
    __shared__ float As[16][128];   // transposed: As[k][m]
    __shared__ float Bs[16][128];
    const int t  = threadIdx.x;
    const int m0 = blockIdx.y * 128;
    const int n0 = blockIdx.x * 128;
    const int a_id = t & 15;
    const int b_id = t >> 4;
    const int lrow = t >> 1, lk = (t & 1) * 8;
    const int brow = t >> 4, bcol = (t & 15) * 8;
    float acc[8][8] = {};

    for (int k0 = 0; k0 < C_; k0 += 16) {
        __syncthreads();
        float4 a0 = *reinterpret_cast<const float4*>(&X[(size_t)(m0 + lrow) * C_ + k0 + lk]);
        float4 a1 = *reinterpret_cast<const float4*>(&X[(size_t)(m0 + lrow) * C_ + k0 + lk + 4]);
        As[lk + 0][lrow] = a0.x; As[lk + 1][lrow] = a0.y;
        As[lk + 2][lrow] = a0.z; As[lk + 3][lrow] = a0.w;
        As[lk + 4][lrow] = a1.x; As[lk + 5][lrow] = a1.y;
        As[lk + 6][lrow] = a1.z; As[lk + 7][lrow] = a1.w;
        *reinterpret_cast<float4*>(&Bs[brow][bcol]) =
            *reinterpret_cast<const float4*>(&W[(size_t)(k0 + brow) * (3 * C_) + n0 + bcol]);
        *reinterpret_cast<float4*>(&Bs[brow][bcol + 4]) =
            *reinterpret_cast<const float4*>(&W[(size_t)(k0 + brow) * (3 * C_) + n0 + bcol + 4]);
        __syncthreads();
        #pragma unroll
        for (int k = 0; k < 16; ++k) {
            float a[8], bfr[8];
            *reinterpret_cast<float4*>(&a[0])   = *reinterpret_cast<const float4*>(&As[k][a_id * 8]);
            *reinterpret_cast<float4*>(&a[4])   = *reinterpret_cast<const float4*>(&As[k][a_id * 8 + 4]);
            *reinterpret_cast<float4*>(&bfr[0]) = *reinterpret_cast<const float4*>(&Bs[k][b_id * 8]);
            *reinterpret_cast<float4*>(&bfr[4]) = *reinterpret_cast<const float4*>(&Bs[k][b_id * 8 + 4]);
            #pragma unroll
            for (int i = 0; i < 8; ++i)
                #pragma unroll
                for (int j = 0; j < 8; ++j)
                    acc[i][j] += a[i] * bfr[j];
        }
    }

    const int nbase = n0 + b_id * 8;
    const int which = nbase >> 10;
    const int h     = (nbase >> 6) & (NH_ - 1);
    const int dbase = nbase & (HD_ - 1);
    bf16* dst = (which == 0) ? Qb : ((which == 1) ? Kb : Vb);
    #pragma unroll
    for (int i = 0; i < 8; ++i) {
        int m  = m0 + a_id * 8 + i;
        int bb = m >> 11;
        int tq = m & (T_ - 1);
        bf16* p = dst + ((size_t)((bb << 4) | h) * T_ + tq) * HD_ + dbase;
        union { unsigned short s[4]; uint2 u; } w0, w1;
        #pragma unroll
        for (int j = 0; j < 4; ++j) { w0.s[j] = f2bf(acc[i][j]); w1.s[j] = f2bf(acc[i][j + 4]); }
        *reinterpret_cast<uint2*>(p)     = w0.u;
        *reinterpret_cast<uint2*>(p + 4) = w1.u;
    }
}

// ---------------------------------------------------------------------------
// Kernel 2: causal flash attention, MFMA bf16 16x16x32.
// Block = 256 threads (4 waves), handles TWO q-tiles {bx, 31-bx} of one head
// (balanced: 33 kv-tiles per block). Wave w owns q-rows [w*16, w*16+16).
// Layouts (verified m89): A-frag lane l: row=l%16, k=(l/16)*8+i (contig);
//   B-frag lane l: col=l%16, k=(l/16)*8+i (contig from row-major B^T);
//   C/D: col=lane&15, row=4*(lane>>4)+r.
// Q,K row-major (+8 pad -> 2-way banks, free); V staged transposed; P via
// per-wave LDS round-trip (acc layout -> A-frag layout).
// ---------------------------------------------------------------------------
__global__ __launch_bounds__(256) void attn_mfma(
    const bf16* __restrict__ Qb, const bf16* __restrict__ Kb,
    const bf16* __restrict__ Vb, bf16* __restrict__ Yb) {
    __shared__ short Qs[64][72];        // [q][d], scaled by 1/8
    __shared__ short Ks[64][72];        // [k][d]
    __shared__ short Vt[64][72];        // [d][k]  (transposed V)
    __shared__ short Ps[4][16][72];     // per-wave P [q][k]

    const int t    = threadIdx.x;
    const int wid  = t >> 6;
    const int lane = t & 63;
    const int c    = lane & 15;         // frag col
    const int g    = lane >> 4;         // frag k-group / row-group
    const int bh   = blockIdx.y;
    const int bb   = bh >> 4, h = bh & (NH_ - 1);
    const bf16* Qh = Qb + (size_t)bh * T_ * HD_;
    const bf16* Kh = Kb + (size_t)bh * T_ * HD_;
    const bf16* Vh = Vb + (size_t)bh * T_ * HD_;
    unsigned short* Yu = reinterpret_cast<unsigned short*>(Yb);

    const int lrow = t >> 2, lcol = (t & 3) * 16;   // cooperative tile loads
    const int qw0 = wid * 16;

    #pragma unroll 1
    for (int pass = 0; pass < 2; ++pass) {
        const int qt = pass ? (31 - (int)blockIdx.x) : (int)blockIdx.x;
        const int q0 = qt * 64;

        __syncthreads();                // all waves done with previous pass
        {   // stage Q (scale 1/8 folded; exact in bf16)
            const bf16* src = &Qh[(size_t)(q0 + lrow) * HD_ + lcol];
            union { uint4 v[2]; unsigned short s[16]; } u, o;
            u.v[0] = *reinterpret_cast<const uint4*>(src);
            u.v[1] = *reinterpret_cast<const uint4*>(src + 8);
            #pragma unroll
            for (int j = 0; j < 16; ++j) o.s[j] = f2bf(bf2f(u.s[j]) * 0.125f);
            *reinterpret_cast<uint4*>(&Qs[lrow][lcol])     = o.v[0];
            *reinterpret_cast<uint4*>(&Qs[lrow][lcol + 8]) = o.v[1];
        }

        float m_run[4], l_run[4];
        f32x4 yacc[4];
        #pragma unroll
        for (int r = 0; r < 4; ++r) { m_run[r] = -1e30f; l_run[r] = 0.f; }
        #pragma unroll
        for (int nt = 0; nt < 4; ++nt) yacc[nt] = (f32x4){0.f, 0.f, 0.f, 0.f};

        #pragma unroll 1
        for (int kt = 0; kt <= qt; ++kt) {
            __syncthreads();            // everyone done reading Ks/Vt
            const int j0 = kt * 64;
            {   // stage K row-major + V transposed
                const bf16* ksrc = &Kh[(size_t)(j0 + lrow) * HD_ + lcol];
                union { uint4 v[2]; unsigned short s[16]; } uk, uv;
                uk.v[0] = *reinterpret_cast<const uint4*>(ksrc);
                uk.v[1] = *reinterpret_cast<const uint4*>(ksrc + 8);
                const bf16* vsrc = &Vh[(size_t)(j0 + lrow) * HD_ + lcol];
                uv.v[0] = *reinterpret_cast<const uint4*>(vsrc);
                uv.v[1] = *reinterpret_cast<const uint4*>(vsrc + 8);
                *reinterpret_cast<uint4*>(&Ks[lrow][lcol])     = uk.v[0];
                *reinterpret_cast<uint4*>(&Ks[lrow][lcol + 8]) = uk.v[1];
                #pragma unroll
                for (int j = 0; j < 16; ++j) Vt[lcol + j][lrow] = (short)uv.s[j];
            }
            __syncthreads();            // staging visible (also Q on kt==0)

            // ---- S = (Q/8) K^T : 8 MFMA ----
            f32x4 sacc[4];
            #pragma unroll
            for (int nt = 0; nt < 4; ++nt) sacc[nt] = (f32x4){0.f, 0.f, 0.f, 0.f};
            #pragma unroll
            for (int kk = 0; kk < 2; ++kk) {
                bf16x8 a = *reinterpret_cast<const bf16x8*>(&Qs[qw0 + c][kk * 32 + g * 8]);
                #pragma unroll
                for (int nt = 0; nt < 4; ++nt) {
                    bf16x8 b = *reinterpret_cast<const bf16x8*>(&Ks[nt * 16 + c][kk * 32 + g * 8]);
                    sacc[nt] = __builtin_amdgcn_mfma_f32_16x16x32_bf16(a, b, sacc[nt], 0, 0, 0);
                }
            }

            // ---- online softmax (rows 4g+r, cols 16nt+c) ----
            const bool diag = (kt == qt);
            #pragma unroll
            for (int r = 0; r < 4; ++r) {
                float s0 = sacc[0][r], s1 = sacc[1][r], s2 = sacc[2][r], s3 = sacc[3][r];
                if (diag) {
                    const int qrow = qw0 + 4 * g + r;
                    if (c      > qrow) s0 = -1e30f;
                    if (16 + c > qrow) s1 = -1e30f;
                    if (32 + c > qrow) s2 = -1e30f;
                    if (48 + c > qrow) s3 = -1e30f;
                }
                float mx = fmaxf(fmaxf(s0, s1), fmaxf(s2, s3));
                #pragma unroll
                for (int off = 1; off < 16; off <<= 1)
                    mx = fmaxf(mx, __shfl_xor(mx, off, 64));
                float mnew = fmaxf(m_run[r], mx);
                float sc   = __expf(m_run[r] - mnew);
                float p0 = __expf(s0 - mnew), p1 = __expf(s1 - mnew);
                float p2 = __expf(s2 - mnew), p3 = __expf(s3 - mnew);
                float ps = p0 + p1 + p2 + p3;
                #pragma unroll
                for (int off = 1; off < 16; off <<= 1)
                    ps += __shfl_xor(ps, off, 64);
                l_run[r] = l_run[r] * sc + ps;
                m_run[r] = mnew;
                #pragma unroll
                for (int nt = 0; nt < 4; ++nt) yacc[nt][r] *= sc;
                const int prow = 4 * g + r;
                Ps[wid][prow][c]      = (short)f2bf(p0);
                Ps[wid][prow][16 + c] = (short)f2bf(p1);
                Ps[wid][prow][32 + c] = (short)f2bf(p2);
                Ps[wid][prow][48 + c] = (short)f2bf(p3);
            }

            // ---- y += P V : 8 MFMA (same-wave LDS round trip for P) ----
            #pragma unroll
            for (int kk = 0; kk < 2; ++kk) {
                bf16x8 pa = *reinterpret_cast<const bf16x8*>(&Ps[wid][c][kk * 32 + g * 8]);
                #pragma unroll
                for (int nt = 0; nt < 4; ++nt) {
                    bf16x8 vb = *reinterpret_cast<const bf16x8*>(&Vt[nt * 16 + c][kk * 32 + g * 8]);
                    yacc[nt] = __builtin_amdgcn_mfma_f32_16x16x32_bf16(pa, vb, yacc[nt], 0, 0, 0);
                }
            }
        }

        // ---- epilogue: normalize, store bf16 Y[B*T][C] ----
        #pragma unroll
        for (int r = 0; r < 4; ++r) {
            float inv = 1.0f / l_run[r];
            const size_t row = (size_t)(bb * T_ + q0 + qw0 + 4 * g + r);
            #pragma unroll
            for (int nt = 0; nt < 4; ++nt) {
                const int col = h * HD_ + 16 * nt + c;
                Yu[row * C_ + col] = f2bf(yacc[nt][r] * inv);
            }
        }
    }
}

// ---------------------------------------------------------------------------
// Kernel 3: projection GEMM (unchanged from round 0)
// ---------------------------------------------------------------------------
__global__ __launch_bounds__(256) void proj_gemm(
    const bf16* __restrict__ Yb, const float* __restrict__ W,
    float* __restrict__ Out) {
    __shared__ float As[16][128];
    __shared__ float Bs[16][128];
    const int t  = threadIdx.x;
    const int m0 = blockIdx.y * 128;
    const int n0 = blockIdx.x * 128;
    const int a_id = t & 15;
    const int b_id = t >> 4;
    const int lrow = t >> 1, lk = (t & 1) * 8;
    const int brow = t >> 4, bcol = (t & 15) * 8;
    float acc[8][8] = {};

    for (int k0 = 0; k0 < C_; k0 += 16) {
        __syncthreads();
        union { uint4 v; unsigned short s[8]; } ua;
        ua.v = *reinterpret_cast<const uint4*>(&Yb[(size_t)(m0 + lrow) * C_ + k0 + lk]);
        #pragma unroll
        for (int j = 0; j < 8; ++j) As[lk + j][lrow] = bf2f(ua.s[j]);
        *reinterpret_cast<float4*>(&Bs[brow][bcol]) =
            *reinterpret_cast<const float4*>(&W[(size_t)(k0 + brow) * C_ + n0 + bcol]);
        *reinterpret_cast<float4*>(&Bs[brow][bcol + 4]) =
            *reinterpret_cast<const float4*>(&W[(size_t)(k0 + brow) * C_ + n0 + bcol + 4]);
        __syncthreads();
        #pragma unroll
        for (int k = 0; k < 16; ++k) {
            float a[8], bfr[8];
            *reinterpret_cast<float4*>(&a[0])   = *reinterpret_cast<const float4*>(&As[k][a_id * 8]);
            *reinterpret_cast<float4*>(&a[4])   = *reinterpret_cast<const float4*>(&As[k][a_id * 8 + 4]);
            *reinterpret_cast<float4*>(&bfr[0]) = *reinterpret_cast<const float4*>(&Bs[k][b_id * 8]);
            *reinterpret_cast<float4*>(&bfr[4]) = *reinterpret_cast<const float4*>(&Bs[k][b_id * 8 + 4]);
            #pragma unroll
            for (int i = 0; i < 8; ++i)
                #pragma unroll
                for (int j = 0; j < 8; ++j)
                    acc[i][j] += a[i] * bfr[j];
        }
    }
    #pragma unroll
    for (int i = 0; i < 8; ++i) {
        int m = m0 + a_id * 8 + i;
        float* p = Out + (size_t)m * C_ + n0 + b_id * 8;
        *reinterpret_cast<float4*>(p)     = *reinterpret_cast<float4*>(&acc[i][0]);
        *reinterpret_cast<float4*>(p + 4) = *reinterpret_cast<float4*>(&acc[i][4]);
    }
}

extern "C" void kernel_launch(void* const* d_in, const int* in_sizes, int n_in,
                              void* d_out, int out_size, void* d_ws, size_t ws_size,
                              hipStream_t stream) {
    const float* x      = (const float*)d_in[0];
    const float* w_qkv  = (const float*)d_in[1];
    const float* w_proj = (const float*)d_in[2];
    float* out = (float*)d_out;

    const size_t HELEMS = (size_t)B_ * NH_ * T_ * HD_;   // 4,194,304
    bf16* Qb = (bf16*)d_ws;
    bf16* Kb = Qb + HELEMS;
    bf16* Vb = Kb + HELEMS;
    bf16* Yb = Vb + HELEMS;                               // total 32 MB

    qkv_gemm<<<dim3(24, 32), 256, 0, stream>>>(x, w_qkv, Qb, Kb, Vb);
    attn_mfma<<<dim3(16, 32), 256, 0, stream>>>(Qb, Kb, Vb, Yb);
    proj_gemm<<<dim3(8, 32), 256, 0, stream>>>(Yb, w_proj, out);
}

// Round 3
// 170.589 us; speedup vs baseline: 5.8092x; 3.0420x over previous
//
#include <hip/hip_runtime.h>
#include <hip/hip_bf16.h>

#define B_ 2
#define T_ 2048
#define C_ 1024
#define NH_ 16
#define HD_ 64

using bf16 = __hip_bfloat16;
typedef __attribute__((ext_vector_type(8))) short bf16x8;
typedef __attribute__((ext_vector_type(4))) float f32x4;

__device__ __forceinline__ float bf2f(unsigned short u) {
    union { unsigned int i; float f; } v;
    v.i = ((unsigned int)u) << 16;
    return v.f;
}
__device__ __forceinline__ unsigned short f2bf(float f) {
    union { float f; unsigned int u; } v;
    v.f = f;
    unsigned int r = v.u + 0x7fffu + ((v.u >> 16) & 1u);  // RNE
    return (unsigned short)(r >> 16);
}
__device__ __forceinline__ void gld_lds16(const void* g, void* l) {
    __builtin_amdgcn_global_load_lds(
        (__attribute__((address_space(1))) void*)g,
        (__attribute__((address_space(3))) void*)l, 16, 0, 0);
}

// ---------------------------------------------------------------------------
// cast_bf16: fp32 -> bf16 elementwise (8 elems/thread)
// ---------------------------------------------------------------------------
__global__ __launch_bounds__(256) void cast_bf16(
    const float* __restrict__ X, unsigned short* __restrict__ Xb, int n) {
    int i = (blockIdx.x * 256 + threadIdx.x) * 8;
    if (i >= n) return;
    float4 f0 = *reinterpret_cast<const float4*>(&X[i]);
    float4 f1 = *reinterpret_cast<const float4*>(&X[i + 4]);
    union { unsigned short s[8]; uint4 v; } o;
    o.s[0] = f2bf(f0.x); o.s[1] = f2bf(f0.y); o.s[2] = f2bf(f0.z); o.s[3] = f2bf(f0.w);
    o.s[4] = f2bf(f1.x); o.s[5] = f2bf(f1.y); o.s[6] = f2bf(f1.z); o.s[7] = f2bf(f1.w);
    *reinterpret_cast<uint4*>(&Xb[i]) = o.v;
}

// ---------------------------------------------------------------------------
// transpose_cast: W[KK][NN] fp32 -> Wt[NN][KK] bf16. 64x64 LDS tile.
// ---------------------------------------------------------------------------
__global__ __launch_bounds__(256) void transpose_cast(
    const float* __restrict__ W, unsigned short* __restrict__ Wt, int NN, int KK) {
    __shared__ short S[64][72];
    const int t = threadIdx.x;
    const int k0 = blockIdx.y * 64, n0 = blockIdx.x * 64;
    const int lr = t >> 2, lc = (t & 3) * 16;
    const float* src = &W[(size_t)(k0 + lr) * NN + n0 + lc];
    #pragma unroll
    for (int j4 = 0; j4 < 4; ++j4) {
        float4 f = *reinterpret_cast<const float4*>(src + j4 * 4);
        S[lc + j4 * 4 + 0][lr] = (short)f2bf(f.x);
        S[lc + j4 * 4 + 1][lr] = (short)f2bf(f.y);
        S[lc + j4 * 4 + 2][lr] = (short)f2bf(f.z);
        S[lc + j4 * 4 + 3][lr] = (short)f2bf(f.w);
    }
    __syncthreads();
    union { unsigned short s[16]; uint4 v[2]; } o;
    #pragma unroll
    for (int j = 0; j < 16; ++j) o.s[j] = (unsigned short)S[lr][lc + j];
    unsigned short* dst = &Wt[(size_t)(n0 + lr) * KK + k0 + lc];
    *reinterpret_cast<uint4*>(dst)     = o.v[0];
    *reinterpret_cast<uint4*>(dst + 8) = o.v[1];
}

// ---------------------------------------------------------------------------
// QKV GEMM, bf16 MFMA. A=Xb[4096][1024], Bt=Wqt[3072][1024] (B^T layout).
// 128x128 tile, BK=32, 4 waves 2x2, 4x4 frags/wave, global_load_lds staging.
// Epilogue scatters head-major into Q/K/V (per-wave 64-col span = one head).
// ---------------------------------------------------------------------------
__global__ __launch_bounds__(256) void qkv_gemm_mfma(
    const unsigned short* __restrict__ A, const unsigned short* __restrict__ Bt,
    unsigned short* __restrict__ Qb, unsigned short* __restrict__ Kb,
    unsigned short* __restrict__ Vb) {
    __shared__ short As[128 * 32];
    __shared__ short Bs[128 * 32];
    const int t = threadIdx.x;
    const int wid = t >> 6, lane = t & 63;
    const int wm = wid >> 1, wn = wid & 1;
    const int c = lane & 15, g = lane >> 4;
    const int m0 = blockIdx.y * 128, n0 = blockIdx.x * 128;
    const int K = C_;
    const int srow = t >> 2, skk = (t & 3) * 8;

    f32x4 acc[4][4];
    #pragma unroll
    for (int i = 0; i < 4; ++i)
        #pragma unroll
        for (int j = 0; j < 4; ++j) acc[i][j] = (f32x4){0.f, 0.f, 0.f, 0.f};

    for (int k0 = 0; k0 < K; k0 += 32) {
        __syncthreads();
        gld_lds16(&A[(size_t)(m0 + srow) * K + k0 + skk],       As + t * 8);
        gld_lds16(&A[(size_t)(m0 + 64 + srow) * K + k0 + skk],  As + 2048 + t * 8);
        gld_lds16(&Bt[(size_t)(n0 + srow) * K + k0 + skk],      Bs + t * 8);
        gld_lds16(&Bt[(size_t)(n0 + 64 + srow) * K + k0 + skk], Bs + 2048 + t * 8);
        __syncthreads();
        bf16x8 af[4], bfv[4];
        #pragma unroll
        for (int mi = 0; mi < 4; ++mi)
            af[mi] = *reinterpret_cast<const bf16x8*>(&As[(wm * 64 + mi * 16 + c) * 32 + g * 8]);
        #pragma unroll
        for (int ni = 0; ni < 4; ++ni)
            bfv[ni] = *reinterpret_cast<const bf16x8*>(&Bs[(wn * 64 + ni * 16 + c) * 32 + g * 8]);
        #pragma unroll
        for (int mi = 0; mi < 4; ++mi)
            #pragma unroll
            for (int ni = 0; ni < 4; ++ni)
                acc[mi][ni] = __builtin_amdgcn_mfma_f32_16x16x32_bf16(af[mi], bfv[ni], acc[mi][ni], 0, 0, 0);
    }

    // epilogue: n-span of this wave = 64 cols => single (which, head)
    const int nbase = n0 + wn * 64;
    const int which = nbase >> 10;
    const int h     = (nbase >> 6) & (NH_ - 1);
    unsigned short* dst = (which == 0) ? Qb : ((which == 1) ? Kb : Vb);
    #pragma unroll
    for (int mi = 0; mi < 4; ++mi)
        #pragma unroll
        for (int r = 0; r < 4; ++r) {
            const int m = m0 + wm * 64 + mi * 16 + 4 * g + r;
            const int bb = m >> 11, tq = m & (T_ - 1);
            unsigned short* p = dst + ((size_t)((bb << 4) | h) * T_ + tq) * HD_;
            #pragma unroll
            for (int ni = 0; ni < 4; ++ni)
                p[ni * 16 + c] = f2bf(acc[mi][ni][r]);
        }
}

// ---------------------------------------------------------------------------
// Projection GEMM, bf16 MFMA. A=Yb[4096][1024] bf16, Bt=Wpt[1024][1024].
// Same structure; fp32 output.
// ---------------------------------------------------------------------------
__global__ __launch_bounds__(256) void proj_gemm_mfma(
    const unsigned short* __restrict__ A, const unsigned short* __restrict__ Bt,
    float* __restrict__ Out) {
    __shared__ short As[128 * 32];
    __shared__ short Bs[128 * 32];
    const int t = threadIdx.x;
    const int wid = t >> 6, lane = t & 63;
    const int wm = wid >> 1, wn = wid & 1;
    const int c = lane & 15, g = lane >> 4;
    const int m0 = blockIdx.y * 128, n0 = blockIdx.x * 128;
    const int K = C_;
    const int srow = t >> 2, skk = (t & 3) * 8;

    f32x4 acc[4][4];
    #pragma unroll
    for (int i = 0; i < 4; ++i)
        #pragma unroll
        for (int j = 0; j < 4; ++j) acc[i][j] = (f32x4){0.f, 0.f, 0.f, 0.f};

    for (int k0 = 0; k0 < K; k0 += 32) {
        __syncthreads();
        gld_lds16(&A[(size_t)(m0 + srow) * K + k0 + skk],       As + t * 8);
        gld_lds16(&A[(size_t)(m0 + 64 + srow) * K + k0 + skk],  As + 2048 + t * 8);
        gld_lds16(&Bt[(size_t)(n0 + srow) * K + k0 + skk],      Bs + t * 8);
        gld_lds16(&Bt[(size_t)(n0 + 64 + srow) * K + k0 + skk], Bs + 2048 + t * 8);
        __syncthreads();
        bf16x8 af[4], bfv[4];
        #pragma unroll
        for (int mi = 0; mi < 4; ++mi)
            af[mi] = *reinterpret_cast<const bf16x8*>(&As[(wm * 64 + mi * 16 + c) * 32 + g * 8]);
        #pragma unroll
        for (int ni = 0; ni < 4; ++ni)
            bfv[ni] = *reinterpret_cast<const bf16x8*>(&Bs[(wn * 64 + ni * 16 + c) * 32 + g * 8]);
        #pragma unroll
        for (int mi = 0; mi < 4; ++mi)
            #pragma unroll
            for (int ni = 0; ni < 4; ++ni)
                acc[mi][ni] = __builtin_amdgcn_mfma_f32_16x16x32_bf16(af[mi], bfv[ni], acc[mi][ni], 0, 0, 0);
    }

    #pragma unroll
    for (int mi = 0; mi < 4; ++mi)
        #pragma unroll
        for (int r = 0; r < 4; ++r) {
            const int m = m0 + wm * 64 + mi * 16 + 4 * g + r;
            float* p = Out + (size_t)m * C_ + n0 + wn * 64;
            #pragma unroll
            for (int ni = 0; ni < 4; ++ni)
                p[ni * 16 + c] = acc[mi][ni][r];
        }
}

// ---------------------------------------------------------------------------
// Flash attention, MFMA bf16 (unchanged from round 1)
// ---------------------------------------------------------------------------
__global__ __launch_bounds__(256) void attn_mfma(
    const bf16* __restrict__ Qb, const bf16* __restrict__ Kb,
    const bf16* __restrict__ Vb, bf16* __restrict__ Yb) {
    __shared__ short Qs[64][72];
    __shared__ short Ks[64][72];
    __shared__ short Vt[64][72];
    __shared__ short Ps[4][16][72];

    const int t    = threadIdx.x;
    const int wid  = t >> 6;
    const int lane = t & 63;
    const int c    = lane & 15;
    const int g    = lane >> 4;
    const int bh   = blockIdx.y;
    const int bb   = bh >> 4, h = bh & (NH_ - 1);
    const bf16* Qh = Qb + (size_t)bh * T_ * HD_;
    const bf16* Kh = Kb + (size_t)bh * T_ * HD_;
    const bf16* Vh = Vb + (size_t)bh * T_ * HD_;
    unsigned short* Yu = reinterpret_cast<unsigned short*>(Yb);

    const int lrow = t >> 2, lcol = (t & 3) * 16;
    const int qw0 = wid * 16;

    #pragma unroll 1
    for (int pass = 0; pass < 2; ++pass) {
        const int qt = pass ? (31 - (int)blockIdx.x) : (int)blockIdx.x;
        const int q0 = qt * 64;

        __syncthreads();
        {
            const bf16* src = &Qh[(size_t)(q0 + lrow) * HD_ + lcol];
            union { uint4 v[2]; unsigned short s[16]; } u, o;
            u.v[0] = *reinterpret_cast<const uint4*>(src);
            u.v[1] = *reinterpret_cast<const uint4*>(src + 8);
            #pragma unroll
            for (int j = 0; j < 16; ++j) o.s[j] = f2bf(bf2f(u.s[j]) * 0.125f);
            *reinterpret_cast<uint4*>(&Qs[lrow][lcol])     = o.v[0];
            *reinterpret_cast<uint4*>(&Qs[lrow][lcol + 8]) = o.v[1];
        }

        float m_run[4], l_run[4];
        f32x4 yacc[4];
        #pragma unroll
        for (int r = 0; r < 4; ++r) { m_run[r] = -1e30f; l_run[r] = 0.f; }
        #pragma unroll
        for (int nt = 0; nt < 4; ++nt) yacc[nt] = (f32x4){0.f, 0.f, 0.f, 0.f};

        #pragma unroll 1
        for (int kt = 0; kt <= qt; ++kt) {
            __syncthreads();
            const int j0 = kt * 64;
            {
                const bf16* ksrc = &Kh[(size_t)(j0 + lrow) * HD_ + lcol];
                union { uint4 v[2]; unsigned short s[16]; } uk, uv;
                uk.v[0] = *reinterpret_cast<const uint4*>(ksrc);
                uk.v[1] = *reinterpret_cast<const uint4*>(ksrc + 8);
                const bf16* vsrc = &Vh[(size_t)(j0 + lrow) * HD_ + lcol];
                uv.v[0] = *reinterpret_cast<const uint4*>(vsrc);
                uv.v[1] = *reinterpret_cast<const uint4*>(vsrc + 8);
                *reinterpret_cast<uint4*>(&Ks[lrow][lcol])     = uk.v[0];
                *reinterpret_cast<uint4*>(&Ks[lrow][lcol + 8]) = uk.v[1];
                #pragma unroll
                for (int j = 0; j < 16; ++j) Vt[lcol + j][lrow] = (short)uv.s[j];
            }
            __syncthreads();

            f32x4 sacc[4];
            #pragma unroll
            for (int nt = 0; nt < 4; ++nt) sacc[nt] = (f32x4){0.f, 0.f, 0.f, 0.f};
            #pragma unroll
            for (int kk = 0; kk < 2; ++kk) {
                bf16x8 a = *reinterpret_cast<const bf16x8*>(&Qs[qw0 + c][kk * 32 + g * 8]);
                #pragma unroll
                for (int nt = 0; nt < 4; ++nt) {
                    bf16x8 b = *reinterpret_cast<const bf16x8*>(&Ks[nt * 16 + c][kk * 32 + g * 8]);
                    sacc[nt] = __builtin_amdgcn_mfma_f32_16x16x32_bf16(a, b, sacc[nt], 0, 0, 0);
                }
            }

            const bool diag = (kt == qt);
            #pragma unroll
            for (int r = 0; r < 4; ++r) {
                float s0 = sacc[0][r], s1 = sacc[1][r], s2 = sacc[2][r], s3 = sacc[3][r];
                if (diag) {
                    const int qrow = qw0 + 4 * g + r;
                    if (c      > qrow) s0 = -1e30f;
                    if (16 + c > qrow) s1 = -1e30f;
                    if (32 + c > qrow) s2 = -1e30f;
                    if (48 + c > qrow) s3 = -1e30f;
                }
                float mx = fmaxf(fmaxf(s0, s1), fmaxf(s2, s3));
                #pragma unroll
                for (int off = 1; off < 16; off <<= 1)
                    mx = fmaxf(mx, __shfl_xor(mx, off, 64));
                float mnew = fmaxf(m_run[r], mx);
                float sc   = __expf(m_run[r] - mnew);
                float p0 = __expf(s0 - mnew), p1 = __expf(s1 - mnew);
                float p2 = __expf(s2 - mnew), p3 = __expf(s3 - mnew);
                float ps = p0 + p1 + p2 + p3;
                #pragma unroll
                for (int off = 1; off < 16; off <<= 1)
                    ps += __shfl_xor(ps, off, 64);
                l_run[r] = l_run[r] * sc + ps;
                m_run[r] = mnew;
                #pragma unroll
                for (int nt = 0; nt < 4; ++nt) yacc[nt][r] *= sc;
                const int prow = 4 * g + r;
                Ps[wid][prow][c]      = (short)f2bf(p0);
                Ps[wid][prow][16 + c] = (short)f2bf(p1);
                Ps[wid][prow][32 + c] = (short)f2bf(p2);
                Ps[wid][prow][48 + c] = (short)f2bf(p3);
            }

            #pragma unroll
            for (int kk = 0; kk < 2; ++kk) {
                bf16x8 pa = *reinterpret_cast<const bf16x8*>(&Ps[wid][c][kk * 32 + g * 8]);
                #pragma unroll
                for (int nt = 0; nt < 4; ++nt) {
                    bf16x8 vb = *reinterpret_cast<const bf16x8*>(&Vt[nt * 16 + c][kk * 32 + g * 8]);
                    yacc[nt] = __builtin_amdgcn_mfma_f32_16x16x32_bf16(pa, vb, yacc[nt], 0, 0, 0);
                }
            }
        }

        #pragma unroll
        for (int r = 0; r < 4; ++r) {
            float inv = 1.0f / l_run[r];
            const size_t row = (size_t)(bb * T_ + q0 + qw0 + 4 * g + r);
            #pragma unroll
            for (int nt = 0; nt < 4; ++nt) {
                const int col = h * HD_ + 16 * nt + c;
                Yu[row * C_ + col] = f2bf(yacc[nt][r] * inv);
            }
        }
    }
}

extern "C" void kernel_launch(void* const* d_in, const int* in_sizes, int n_in,
                              void* d_out, int out_size, void* d_ws, size_t ws_size,
                              hipStream_t stream) {
    const float* x      = (const float*)d_in[0];
    const float* w_qkv  = (const float*)d_in[1];
    const float* w_proj = (const float*)d_in[2];
    float* out = (float*)d_out;

    const size_t HELEMS = (size_t)B_ * NH_ * T_ * HD_;   // 4,194,304
    unsigned short* Qb  = (unsigned short*)d_ws;
    unsigned short* Kb  = Qb + HELEMS;
    unsigned short* Vb  = Kb + HELEMS;
    unsigned short* Xb  = Vb + HELEMS;        // aliased: Yb reuses Xb after qkv
    unsigned short* Yb  = Xb;
    unsigned short* Wqt = Xb + HELEMS;        // 3072x1024
    unsigned short* Wpt = Wqt;                // aliased: cast after qkv_gemm

    const int NX = B_ * T_ * C_;              // 4,194,304
    cast_bf16<<<NX / (256 * 8), 256, 0, stream>>>(x, Xb, NX);
    transpose_cast<<<dim3(48, 16), 256, 0, stream>>>(w_qkv, Wqt, 3 * C_, C_);
    qkv_gemm_mfma<<<dim3(24, 32), 256, 0, stream>>>(Xb, Wqt, Qb, Kb, Vb);
    transpose_cast<<<dim3(16, 16), 256, 0, stream>>>(w_proj, Wpt, C_, C_);
    attn_mfma<<<dim3(16, 32), 256, 0, stream>>>((const bf16*)Qb, (const bf16*)Kb,
                                                (const bf16*)Vb, (bf16*)Yb);
    proj_gemm_mfma<<<dim3(8, 32), 256, 0, stream>>>(Yb, Wpt, out);
}

// Round 4
// 167.655 us; speedup vs baseline: 5.9108x; 1.0175x over previous
//
#include <hip/hip_runtime.h>
#include <hip/hip_bf16.h>

#define B_ 2
#define T_ 2048
#define C_ 1024
#define NH_ 16
#define HD_ 64

using bf16 = __hip_bfloat16;
typedef __attribute__((ext_vector_type(8))) short bf16x8;
typedef __attribute__((ext_vector_type(4))) float f32x4;

__device__ __forceinline__ float bf2f(unsigned short u) {
    union { unsigned int i; float f; } v;
    v.i = ((unsigned int)u) << 16;
    return v.f;
}
__device__ __forceinline__ unsigned short f2bf(float f) {
    union { float f; unsigned int u; } v;
    v.f = f;
    unsigned int r = v.u + 0x7fffu + ((v.u >> 16) & 1u);  // RNE
    return (unsigned short)(r >> 16);
}
__device__ __forceinline__ void gld_lds16(const void* g, void* l) {
    __builtin_amdgcn_global_load_lds(
        (__attribute__((address_space(1))) void*)g,
        (__attribute__((address_space(3))) void*)l, 16, 0, 0);
}

// ---------------------------------------------------------------------------
// cast_bf16: fp32 -> bf16 elementwise (8 elems/thread)
// ---------------------------------------------------------------------------
__global__ __launch_bounds__(256) void cast_bf16(
    const float* __restrict__ X, unsigned short* __restrict__ Xb, int n) {
    int i = (blockIdx.x * 256 + threadIdx.x) * 8;
    if (i >= n) return;
    float4 f0 = *reinterpret_cast<const float4*>(&X[i]);
    float4 f1 = *reinterpret_cast<const float4*>(&X[i + 4]);
    union { unsigned short s[8]; uint4 v; } o;
    o.s[0] = f2bf(f0.x); o.s[1] = f2bf(f0.y); o.s[2] = f2bf(f0.z); o.s[3] = f2bf(f0.w);
    o.s[4] = f2bf(f1.x); o.s[5] = f2bf(f1.y); o.s[6] = f2bf(f1.z); o.s[7] = f2bf(f1.w);
    *reinterpret_cast<uint4*>(&Xb[i]) = o.v;
}

// ---------------------------------------------------------------------------
// transpose_cast: W[KK][NN] fp32 -> Wt[NN][KK] bf16. 64x64 LDS tile.
// ---------------------------------------------------------------------------
__global__ __launch_bounds__(256) void transpose_cast(
    const float* __restrict__ W, unsigned short* __restrict__ Wt, int NN, int KK) {
    __shared__ short S[64][72];
    const int t = threadIdx.x;
    const int k0 = blockIdx.y * 64, n0 = blockIdx.x * 64;
    const int lr = t >> 2, lc = (t & 3) * 16;
    const float* src = &W[(size_t)(k0 + lr) * NN + n0 + lc];
    #pragma unroll
    for (int j4 = 0; j4 < 4; ++j4) {
        float4 f = *reinterpret_cast<const float4*>(src + j4 * 4);
        S[lc + j4 * 4 + 0][lr] = (short)f2bf(f.x);
        S[lc + j4 * 4 + 1][lr] = (short)f2bf(f.y);
        S[lc + j4 * 4 + 2][lr] = (short)f2bf(f.z);
        S[lc + j4 * 4 + 3][lr] = (short)f2bf(f.w);
    }
    __syncthreads();
    union { unsigned short s[16]; uint4 v[2]; } o;
    #pragma unroll
    for (int j = 0; j < 16; ++j) o.s[j] = (unsigned short)S[lr][lc + j];
    unsigned short* dst = &Wt[(size_t)(n0 + lr) * KK + k0 + lc];
    *reinterpret_cast<uint4*>(dst)     = o.v[0];
    *reinterpret_cast<uint4*>(dst + 8) = o.v[1];
}

// ---------------------------------------------------------------------------
// QKV GEMM, bf16 MFMA. A=Xb[4096][1024], Bt=Wqt[3072][1024] (B^T layout).
// Q columns pre-scaled by 1/8 (softmax scale folded in).
// ---------------------------------------------------------------------------
__global__ __launch_bounds__(256) void qkv_gemm_mfma(
    const unsigned short* __restrict__ A, const unsigned short* __restrict__ Bt,
    unsigned short* __restrict__ Qb, unsigned short* __restrict__ Kb,
    unsigned short* __restrict__ Vb) {
    __shared__ short As[128 * 32];
    __shared__ short Bs[128 * 32];
    const int t = threadIdx.x;
    const int wid = t >> 6, lane = t & 63;
    const int wm = wid >> 1, wn = wid & 1;
    const int c = lane & 15, g = lane >> 4;
    const int m0 = blockIdx.y * 128, n0 = blockIdx.x * 128;
    const int K = C_;
    const int srow = t >> 2, skk = (t & 3) * 8;

    f32x4 acc[4][4];
    #pragma unroll
    for (int i = 0; i < 4; ++i)
        #pragma unroll
        for (int j = 0; j < 4; ++j) acc[i][j] = (f32x4){0.f, 0.f, 0.f, 0.f};

    for (int k0 = 0; k0 < K; k0 += 32) {
        __syncthreads();
        gld_lds16(&A[(size_t)(m0 + srow) * K + k0 + skk],       As + t * 8);
        gld_lds16(&A[(size_t)(m0 + 64 + srow) * K + k0 + skk],  As + 2048 + t * 8);
        gld_lds16(&Bt[(size_t)(n0 + srow) * K + k0 + skk],      Bs + t * 8);
        gld_lds16(&Bt[(size_t)(n0 + 64 + srow) * K + k0 + skk], Bs + 2048 + t * 8);
        __syncthreads();
        bf16x8 af[4], bfv[4];
        #pragma unroll
        for (int mi = 0; mi < 4; ++mi)
            af[mi] = *reinterpret_cast<const bf16x8*>(&As[(wm * 64 + mi * 16 + c) * 32 + g * 8]);
        #pragma unroll
        for (int ni = 0; ni < 4; ++ni)
            bfv[ni] = *reinterpret_cast<const bf16x8*>(&Bs[(wn * 64 + ni * 16 + c) * 32 + g * 8]);
        #pragma unroll
        for (int mi = 0; mi < 4; ++mi)
            #pragma unroll
            for (int ni = 0; ni < 4; ++ni)
                acc[mi][ni] = __builtin_amdgcn_mfma_f32_16x16x32_bf16(af[mi], bfv[ni], acc[mi][ni], 0, 0, 0);
    }

    // epilogue: n-span of this wave = 64 cols => single (which, head)
    const int nbase = n0 + wn * 64;
    const int which = nbase >> 10;
    const int h     = (nbase >> 6) & (NH_ - 1);
    const float scale = (which == 0) ? 0.125f : 1.0f;   // fold 1/sqrt(HD) into Q
    unsigned short* dst = (which == 0) ? Qb : ((which == 1) ? Kb : Vb);
    #pragma unroll
    for (int mi = 0; mi < 4; ++mi)
        #pragma unroll
        for (int r = 0; r < 4; ++r) {
            const int m = m0 + wm * 64 + mi * 16 + 4 * g + r;
            const int bb = m >> 11, tq = m & (T_ - 1);
            unsigned short* p = dst + ((size_t)((bb << 4) | h) * T_ + tq) * HD_;
            #pragma unroll
            for (int ni = 0; ni < 4; ++ni)
                p[ni * 16 + c] = f2bf(acc[mi][ni][r] * scale);
        }
}

// ---------------------------------------------------------------------------
// Projection GEMM, bf16 MFMA. A=Yb[4096][1024] bf16, Bt=Wpt[1024][1024].
// ---------------------------------------------------------------------------
__global__ __launch_bounds__(256) void proj_gemm_mfma(
    const unsigned short* __restrict__ A, const unsigned short* __restrict__ Bt,
    float* __restrict__ Out) {
    __shared__ short As[128 * 32];
    __shared__ short Bs[128 * 32];
    const int t = threadIdx.x;
    const int wid = t >> 6, lane = t & 63;
    const int wm = wid >> 1, wn = wid & 1;
    const int c = lane & 15, g = lane >> 4;
    const int m0 = blockIdx.y * 128, n0 = blockIdx.x * 128;
    const int K = C_;
    const int srow = t >> 2, skk = (t & 3) * 8;

    f32x4 acc[4][4];
    #pragma unroll
    for (int i = 0; i < 4; ++i)
        #pragma unroll
        for (int j = 0; j < 4; ++j) acc[i][j] = (f32x4){0.f, 0.f, 0.f, 0.f};

    for (int k0 = 0; k0 < K; k0 += 32) {
        __syncthreads();
        gld_lds16(&A[(size_t)(m0 + srow) * K + k0 + skk],       As + t * 8);
        gld_lds16(&A[(size_t)(m0 + 64 + srow) * K + k0 + skk],  As + 2048 + t * 8);
        gld_lds16(&Bt[(size_t)(n0 + srow) * K + k0 + skk],      Bs + t * 8);
        gld_lds16(&Bt[(size_t)(n0 + 64 + srow) * K + k0 + skk], Bs + 2048 + t * 8);
        __syncthreads();
        bf16x8 af[4], bfv[4];
        #pragma unroll
        for (int mi = 0; mi < 4; ++mi)
            af[mi] = *reinterpret_cast<const bf16x8*>(&As[(wm * 64 + mi * 16 + c) * 32 + g * 8]);
        #pragma unroll
        for (int ni = 0; ni < 4; ++ni)
            bfv[ni] = *reinterpret_cast<const bf16x8*>(&Bs[(wn * 64 + ni * 16 + c) * 32 + g * 8]);
        #pragma unroll
        for (int mi = 0; mi < 4; ++mi)
            #pragma unroll
            for (int ni = 0; ni < 4; ++ni)
                acc[mi][ni] = __builtin_amdgcn_mfma_f32_16x16x32_bf16(af[mi], bfv[ni], acc[mi][ni], 0, 0, 0);
    }

    #pragma unroll
    for (int mi = 0; mi < 4; ++mi)
        #pragma unroll
        for (int r = 0; r < 4; ++r) {
            const int m = m0 + wm * 64 + mi * 16 + 4 * g + r;
            float* p = Out + (size_t)m * C_ + n0 + wn * 64;
            #pragma unroll
            for (int ni = 0; ni < 4; ++ni)
                p[ni * 16 + c] = acc[mi][ni][r];
        }
}

// ---------------------------------------------------------------------------
// Flash attention, MFMA bf16. ONE q-tile (64 rows) per block, 4 waves.
// Grid: 1024 linear. Decode groups bh%8 per XCD (K/V L2 locality) and
// staggers qt by (31-bx+by)&31 so co-resident blocks have balanced work.
// Q pre-scaled by 1/8 in qkv epilogue. Softmax sum reduction deferred to
// epilogue (per-lane partials; rescale factor is row-uniform so exact).
// ---------------------------------------------------------------------------
__global__ __launch_bounds__(256) void attn_mfma(
    const bf16* __restrict__ Qb, const bf16* __restrict__ Kb,
    const bf16* __restrict__ Vb, bf16* __restrict__ Yb) {
    __shared__ short Qs[64][72];
    __shared__ short Ks[64][72];
    __shared__ short Vt[64][72];
    __shared__ short Ps[4][16][72];

    const int t    = threadIdx.x;
    const int wid  = t >> 6;
    const int lane = t & 63;
    const int c    = lane & 15;
    const int g    = lane >> 4;

    // --- block decode: XCD grouping + balanced qt stagger ---
    const int d   = blockIdx.x;
    const int xcd = d & 7;
    const int tt  = d >> 3;                  // 0..127
    const int bx  = tt & 31;
    const int by  = ((tt >> 5) << 3) | xcd;  // bh, grouped by %8 per XCD
    const int qt  = (31 - bx + by) & 31;
    const int bh  = by;

    const int bb   = bh >> 4, h = bh & (NH_ - 1);
    const int q0   = qt * 64;
    const bf16* Qh = Qb + (size_t)bh * T_ * HD_;
    const bf16* Kh = Kb + (size_t)bh * T_ * HD_;
    const bf16* Vh = Vb + (size_t)bh * T_ * HD_;
    unsigned short* Yu = reinterpret_cast<unsigned short*>(Yb);

    const int lrow = t >> 2, lcol = (t & 3) * 16;
    const int qw0 = wid * 16;

    {   // stage Q (already scaled)
        const bf16* src = &Qh[(size_t)(q0 + lrow) * HD_ + lcol];
        *reinterpret_cast<uint4*>(&Qs[lrow][lcol])     = *reinterpret_cast<const uint4*>(src);
        *reinterpret_cast<uint4*>(&Qs[lrow][lcol + 8]) = *reinterpret_cast<const uint4*>(src + 8);
    }

    float m_run[4], l_run[4];
    f32x4 yacc[4];
    #pragma unroll
    for (int r = 0; r < 4; ++r) { m_run[r] = -1e30f; l_run[r] = 0.f; }
    #pragma unroll
    for (int nt = 0; nt < 4; ++nt) yacc[nt] = (f32x4){0.f, 0.f, 0.f, 0.f};

    #pragma unroll 1
    for (int kt = 0; kt <= qt; ++kt) {
        __syncthreads();            // everyone done reading Ks/Vt
        const int j0 = kt * 64;
        {   // stage K row-major + V transposed
            const bf16* ksrc = &Kh[(size_t)(j0 + lrow) * HD_ + lcol];
            union { uint4 v[2]; unsigned short s[16]; } uk, uv;
            uk.v[0] = *reinterpret_cast<const uint4*>(ksrc);
            uk.v[1] = *reinterpret_cast<const uint4*>(ksrc + 8);
            const bf16* vsrc = &Vh[(size_t)(j0 + lrow) * HD_ + lcol];
            uv.v[0] = *reinterpret_cast<const uint4*>(vsrc);
            uv.v[1] = *reinterpret_cast<const uint4*>(vsrc + 8);
            *reinterpret_cast<uint4*>(&Ks[lrow][lcol])     = uk.v[0];
            *reinterpret_cast<uint4*>(&Ks[lrow][lcol + 8]) = uk.v[1];
            #pragma unroll
            for (int j = 0; j < 16; ++j) Vt[lcol + j][lrow] = (short)uv.s[j];
        }
        __syncthreads();            // staging visible (also Q on kt==0)

        // ---- S = (Q/8) K^T : 8 MFMA ----
        f32x4 sacc[4];
        #pragma unroll
        for (int nt = 0; nt < 4; ++nt) sacc[nt] = (f32x4){0.f, 0.f, 0.f, 0.f};
        __builtin_amdgcn_s_setprio(1);
        #pragma unroll
        for (int kk = 0; kk < 2; ++kk) {
            bf16x8 a = *reinterpret_cast<const bf16x8*>(&Qs[qw0 + c][kk * 32 + g * 8]);
            #pragma unroll
            for (int nt = 0; nt < 4; ++nt) {
                bf16x8 b = *reinterpret_cast<const bf16x8*>(&Ks[nt * 16 + c][kk * 32 + g * 8]);
                sacc[nt] = __builtin_amdgcn_mfma_f32_16x16x32_bf16(a, b, sacc[nt], 0, 0, 0);
            }
        }
        __builtin_amdgcn_s_setprio(0);

        // ---- online softmax (rows 4g+r, cols 16nt+c) ----
        const bool diag = (kt == qt);
        #pragma unroll
        for (int r = 0; r < 4; ++r) {
            float s0 = sacc[0][r], s1 = sacc[1][r], s2 = sacc[2][r], s3 = sacc[3][r];
            if (diag) {
                const int qrow = qw0 + 4 * g + r;
                if (c      > qrow) s0 = -1e30f;
                if (16 + c > qrow) s1 = -1e30f;
                if (32 + c > qrow) s2 = -1e30f;
                if (48 + c > qrow) s3 = -1e30f;
            }
            float mx = fmaxf(fmaxf(s0, s1), fmaxf(s2, s3));
            #pragma unroll
            for (int off = 1; off < 16; off <<= 1)
                mx = fmaxf(mx, __shfl_xor(mx, off, 64));
            float mnew = fmaxf(m_run[r], mx);
            float sc   = __expf(m_run[r] - mnew);
            float p0 = __expf(s0 - mnew), p1 = __expf(s1 - mnew);
            float p2 = __expf(s2 - mnew), p3 = __expf(s3 - mnew);
            l_run[r] = l_run[r] * sc + (p0 + p1 + p2 + p3);   // per-lane partial
            m_run[r] = mnew;
            #pragma unroll
            for (int nt = 0; nt < 4; ++nt) yacc[nt][r] *= sc;
            const int prow = 4 * g + r;
            Ps[wid][prow][c]      = (short)f2bf(p0);
            Ps[wid][prow][16 + c] = (short)f2bf(p1);
            Ps[wid][prow][32 + c] = (short)f2bf(p2);
            Ps[wid][prow][48 + c] = (short)f2bf(p3);
        }

        // ---- y += P V : 8 MFMA (same-wave LDS round trip for P) ----
        __builtin_amdgcn_s_setprio(1);
        #pragma unroll
        for (int kk = 0; kk < 2; ++kk) {
            bf16x8 pa = *reinterpret_cast<const bf16x8*>(&Ps[wid][c][kk * 32 + g * 8]);
            #pragma unroll
            for (int nt = 0; nt < 4; ++nt) {
                bf16x8 vb = *reinterpret_cast<const bf16x8*>(&Vt[nt * 16 + c][kk * 32 + g * 8]);
                yacc[nt] = __builtin_amdgcn_mfma_f32_16x16x32_bf16(pa, vb, yacc[nt], 0, 0, 0);
            }
        }
        __builtin_amdgcn_s_setprio(0);
    }

    // ---- epilogue: reduce l across the 16 lanes of each row, store Y ----
    #pragma unroll
    for (int r = 0; r < 4; ++r) {
        float l = l_run[r];
        #pragma unroll
        for (int off = 1; off < 16; off <<= 1)
            l += __shfl_xor(l, off, 64);
        float inv = 1.0f / l;
        const size_t row = (size_t)(bb * T_ + q0 + qw0 + 4 * g + r);
        #pragma unroll
        for (int nt = 0; nt < 4; ++nt) {
            const int col = h * HD_ + 16 * nt + c;
            Yu[row * C_ + col] = f2bf(yacc[nt][r] * inv);
        }
    }
}

extern "C" void kernel_launch(void* const* d_in, const int* in_sizes, int n_in,
                              void* d_out, int out_size, void* d_ws, size_t ws_size,
                              hipStream_t stream) {
    const float* x      = (const float*)d_in[0];
    const float* w_qkv  = (const float*)d_in[1];
    const float* w_proj = (const float*)d_in[2];
    float* out = (float*)d_out;

    const size_t HELEMS = (size_t)B_ * NH_ * T_ * HD_;   // 4,194,304
    unsigned short* Qb  = (unsigned short*)d_ws;
    unsigned short* Kb  = Qb + HELEMS;
    unsigned short* Vb  = Kb + HELEMS;
    unsigned short* Xb  = Vb + HELEMS;        // aliased: Yb reuses Xb after qkv
    unsigned short* Yb  = Xb;
    unsigned short* Wqt = Xb + HELEMS;        // 3072x1024
    unsigned short* Wpt = Wqt;                // aliased: cast after qkv_gemm

    const int NX = B_ * T_ * C_;              // 4,194,304
    cast_bf16<<<NX / (256 * 8), 256, 0, stream>>>(x, Xb, NX);
    transpose_cast<<<dim3(48, 16), 256, 0, stream>>>(w_qkv, Wqt, 3 * C_, C_);
    qkv_gemm_mfma<<<dim3(24, 32), 256, 0, stream>>>(Xb, Wqt, Qb, Kb, Vb);
    transpose_cast<<<dim3(16, 16), 256, 0, stream>>>(w_proj, Wpt, C_, C_);
    attn_mfma<<<1024, 256, 0, stream>>>((const bf16*)Qb, (const bf16*)Kb,
                                        (const bf16*)Vb, (bf16*)Yb);
    proj_gemm_mfma<<<dim3(8, 32), 256, 0, stream>>>(Yb, Wpt, out);
}

// Round 5
// 152.609 us; speedup vs baseline: 6.4936x; 1.0986x over previous
//
#include <hip/hip_runtime.h>
#include <hip/hip_bf16.h>

#define B_ 2
#define T_ 2048
#define C_ 1024
#define NH_ 16
#define HD_ 64

using bf16 = __hip_bfloat16;
typedef __attribute__((ext_vector_type(8))) short bf16x8;
typedef __attribute__((ext_vector_type(4))) float f32x4;

__device__ __forceinline__ float bf2f(unsigned short u) {
    union { unsigned int i; float f; } v;
    v.i = ((unsigned int)u) << 16;
    return v.f;
}
__device__ __forceinline__ unsigned short f2bf(float f) {
    union { float f; unsigned int u; } v;
    v.f = f;
    unsigned int r = v.u + 0x7fffu + ((v.u >> 16) & 1u);  // RNE
    return (unsigned short)(r >> 16);
}
__device__ __forceinline__ void gld_lds16(const void* g, void* l) {
    __builtin_amdgcn_global_load_lds(
        (__attribute__((address_space(1))) void*)g,
        (__attribute__((address_space(3))) void*)l, 16, 0, 0);
}

// ---------------------------------------------------------------------------
// cast_bf16: fp32 -> bf16 elementwise (8 elems/thread)
// ---------------------------------------------------------------------------
__global__ __launch_bounds__(256) void cast_bf16(
    const float* __restrict__ X, unsigned short* __restrict__ Xb, int n) {
    int i = (blockIdx.x * 256 + threadIdx.x) * 8;
    if (i >= n) return;
    float4 f0 = *reinterpret_cast<const float4*>(&X[i]);
    float4 f1 = *reinterpret_cast<const float4*>(&X[i + 4]);
    union { unsigned short s[8]; uint4 v; } o;
    o.s[0] = f2bf(f0.x); o.s[1] = f2bf(f0.y); o.s[2] = f2bf(f0.z); o.s[3] = f2bf(f0.w);
    o.s[4] = f2bf(f1.x); o.s[5] = f2bf(f1.y); o.s[6] = f2bf(f1.z); o.s[7] = f2bf(f1.w);
    *reinterpret_cast<uint4*>(&Xb[i]) = o.v;
}

// ---------------------------------------------------------------------------
// transpose_cast: W[KK][NN] fp32 -> Wt[NN][KK] bf16. 64x64 LDS tile.
// ---------------------------------------------------------------------------
__global__ __launch_bounds__(256) void transpose_cast(
    const float* __restrict__ W, unsigned short* __restrict__ Wt, int NN, int KK) {
    __shared__ short S[64][72];
    const int t = threadIdx.x;
    const int k0 = blockIdx.y * 64, n0 = blockIdx.x * 64;
    const int lr = t >> 2, lc = (t & 3) * 16;
    const float* src = &W[(size_t)(k0 + lr) * NN + n0 + lc];
    #pragma unroll
    for (int j4 = 0; j4 < 4; ++j4) {
        float4 f = *reinterpret_cast<const float4*>(src + j4 * 4);
        S[lc + j4 * 4 + 0][lr] = (short)f2bf(f.x);
        S[lc + j4 * 4 + 1][lr] = (short)f2bf(f.y);
        S[lc + j4 * 4 + 2][lr] = (short)f2bf(f.z);
        S[lc + j4 * 4 + 3][lr] = (short)f2bf(f.w);
    }
    __syncthreads();
    union { unsigned short s[16]; uint4 v[2]; } o;
    #pragma unroll
    for (int j = 0; j < 16; ++j) o.s[j] = (unsigned short)S[lr][lc + j];
    unsigned short* dst = &Wt[(size_t)(n0 + lr) * KK + k0 + lc];
    *reinterpret_cast<uint4*>(dst)     = o.v[0];
    *reinterpret_cast<uint4*>(dst + 8) = o.v[1];
}

// ---------------------------------------------------------------------------
// QKV GEMM, bf16 MFMA. A=Xb[4096][1024], Bt=Wqt[3072][1024] (B^T layout).
// Q pre-scaled by 1/8. V stored TRANSPOSED: Vb layout [bh][d][tq].
// ---------------------------------------------------------------------------
__global__ __launch_bounds__(256) void qkv_gemm_mfma(
    const unsigned short* __restrict__ A, const unsigned short* __restrict__ Bt,
    unsigned short* __restrict__ Qb, unsigned short* __restrict__ Kb,
    unsigned short* __restrict__ Vb) {
    __shared__ short As[128 * 32];
    __shared__ short Bs[128 * 32];
    const int t = threadIdx.x;
    const int wid = t >> 6, lane = t & 63;
    const int wm = wid >> 1, wn = wid & 1;
    const int c = lane & 15, g = lane >> 4;
    const int m0 = blockIdx.y * 128, n0 = blockIdx.x * 128;
    const int K = C_;
    const int srow = t >> 2, skk = (t & 3) * 8;

    f32x4 acc[4][4];
    #pragma unroll
    for (int i = 0; i < 4; ++i)
        #pragma unroll
        for (int j = 0; j < 4; ++j) acc[i][j] = (f32x4){0.f, 0.f, 0.f, 0.f};

    for (int k0 = 0; k0 < K; k0 += 32) {
        __syncthreads();
        gld_lds16(&A[(size_t)(m0 + srow) * K + k0 + skk],       As + t * 8);
        gld_lds16(&A[(size_t)(m0 + 64 + srow) * K + k0 + skk],  As + 2048 + t * 8);
        gld_lds16(&Bt[(size_t)(n0 + srow) * K + k0 + skk],      Bs + t * 8);
        gld_lds16(&Bt[(size_t)(n0 + 64 + srow) * K + k0 + skk], Bs + 2048 + t * 8);
        __syncthreads();
        bf16x8 af[4], bfv[4];
        #pragma unroll
        for (int mi = 0; mi < 4; ++mi)
            af[mi] = *reinterpret_cast<const bf16x8*>(&As[(wm * 64 + mi * 16 + c) * 32 + g * 8]);
        #pragma unroll
        for (int ni = 0; ni < 4; ++ni)
            bfv[ni] = *reinterpret_cast<const bf16x8*>(&Bs[(wn * 64 + ni * 16 + c) * 32 + g * 8]);
        #pragma unroll
        for (int mi = 0; mi < 4; ++mi)
            #pragma unroll
            for (int ni = 0; ni < 4; ++ni)
                acc[mi][ni] = __builtin_amdgcn_mfma_f32_16x16x32_bf16(af[mi], bfv[ni], acc[mi][ni], 0, 0, 0);
    }

    // epilogue: n-span of this wave = 64 cols => single (which, head)
    const int nbase = n0 + wn * 64;
    const int which = nbase >> 10;
    const int h     = (nbase >> 6) & (NH_ - 1);
    if (which == 2) {
        // V: store transposed [bh][d][tq]
        #pragma unroll
        for (int mi = 0; mi < 4; ++mi)
            #pragma unroll
            for (int r = 0; r < 4; ++r) {
                const int m = m0 + wm * 64 + mi * 16 + 4 * g + r;
                const int bb = m >> 11, tq = m & (T_ - 1);
                unsigned short* p = Vb + (size_t)((bb << 4) | h) * HD_ * T_ + tq;
                #pragma unroll
                for (int ni = 0; ni < 4; ++ni)
                    p[(size_t)(ni * 16 + c) * T_] = f2bf(acc[mi][ni][r]);
            }
    } else {
        const float scale = (which == 0) ? 0.125f : 1.0f;   // fold 1/sqrt(HD) into Q
        unsigned short* dst = (which == 0) ? Qb : Kb;
        #pragma unroll
        for (int mi = 0; mi < 4; ++mi)
            #pragma unroll
            for (int r = 0; r < 4; ++r) {
                const int m = m0 + wm * 64 + mi * 16 + 4 * g + r;
                const int bb = m >> 11, tq = m & (T_ - 1);
                unsigned short* p = dst + ((size_t)((bb << 4) | h) * T_ + tq) * HD_;
                #pragma unroll
                for (int ni = 0; ni < 4; ++ni)
                    p[ni * 16 + c] = f2bf(acc[mi][ni][r] * scale);
            }
    }
}

// ---------------------------------------------------------------------------
// Projection GEMM, bf16 MFMA. A=Yb[4096][1024] bf16, Bt=Wpt[1024][1024].
// ---------------------------------------------------------------------------
__global__ __launch_bounds__(256) void proj_gemm_mfma(
    const unsigned short* __restrict__ A, const unsigned short* __restrict__ Bt,
    float* __restrict__ Out) {
    __shared__ short As[128 * 32];
    __shared__ short Bs[128 * 32];
    const int t = threadIdx.x;
    const int wid = t >> 6, lane = t & 63;
    const int wm = wid >> 1, wn = wid & 1;
    const int c = lane & 15, g = lane >> 4;
    const int m0 = blockIdx.y * 128, n0 = blockIdx.x * 128;
    const int K = C_;
    const int srow = t >> 2, skk = (t & 3) * 8;

    f32x4 acc[4][4];
    #pragma unroll
    for (int i = 0; i < 4; ++i)
        #pragma unroll
        for (int j = 0; j < 4; ++j) acc[i][j] = (f32x4){0.f, 0.f, 0.f, 0.f};

    for (int k0 = 0; k0 < K; k0 += 32) {
        __syncthreads();
        gld_lds16(&A[(size_t)(m0 + srow) * K + k0 + skk],       As + t * 8);
        gld_lds16(&A[(size_t)(m0 + 64 + srow) * K + k0 + skk],  As + 2048 + t * 8);
        gld_lds16(&Bt[(size_t)(n0 + srow) * K + k0 + skk],      Bs + t * 8);
        gld_lds16(&Bt[(size_t)(n0 + 64 + srow) * K + k0 + skk], Bs + 2048 + t * 8);
        __syncthreads();
        bf16x8 af[4], bfv[4];
        #pragma unroll
        for (int mi = 0; mi < 4; ++mi)
            af[mi] = *reinterpret_cast<const bf16x8*>(&As[(wm * 64 + mi * 16 + c) * 32 + g * 8]);
        #pragma unroll
        for (int ni = 0; ni < 4; ++ni)
            bfv[ni] = *reinterpret_cast<const bf16x8*>(&Bs[(wn * 64 + ni * 16 + c) * 32 + g * 8]);
        #pragma unroll
        for (int mi = 0; mi < 4; ++mi)
            #pragma unroll
            for (int ni = 0; ni < 4; ++ni)
                acc[mi][ni] = __builtin_amdgcn_mfma_f32_16x16x32_bf16(af[mi], bfv[ni], acc[mi][ni], 0, 0, 0);
    }

    #pragma unroll
    for (int mi = 0; mi < 4; ++mi)
        #pragma unroll
        for (int r = 0; r < 4; ++r) {
            const int m = m0 + wm * 64 + mi * 16 + 4 * g + r;
            float* p = Out + (size_t)m * C_ + n0 + wn * 64;
            #pragma unroll
            for (int ni = 0; ni < 4; ++ni)
                p[ni * 16 + c] = acc[mi][ni][r];
        }
}

// ---------------------------------------------------------------------------
// Flash attention, MFMA bf16, swapped QK^T.
// One q-tile (64 rows) per block, 4 waves; wave owns q rows [wid*16, +16).
// QK^T computed as mfma(K, Q) -> lane (c,g) holds S[q=qw0+c][j=nt*16+4g+r]:
// one q-row per lane => softmax = in-lane max/exp + 2 shfl; P written as
// vectorized 8B; rescale factors moved to PV layout via 4 ds_bpermute.
// V is pre-transposed in global ([bh][d][T]) => staging is a vector copy.
// T14: next tile's global loads issued before compute, LDS-written after.
// ---------------------------------------------------------------------------
__global__ __launch_bounds__(256) void attn_mfma(
    const unsigned short* __restrict__ Qb, const unsigned short* __restrict__ Kb,
    const unsigned short* __restrict__ Vt_g, unsigned short* __restrict__ Yu) {
    __shared__ short Qs[64][72];        // [q][d], pre-scaled by 1/8
    __shared__ short Ks[64][72];        // [j][d]
    __shared__ short Vt[64][72];        // [d][j]  (from transposed global V)
    __shared__ short Ps[4][16][72];     // per-wave P [q][j]

    const int t    = threadIdx.x;
    const int wid  = t >> 6;
    const int lane = t & 63;
    const int c    = lane & 15;
    const int g    = lane >> 4;

    // --- block decode: XCD grouping + balanced qt stagger ---
    const int d   = blockIdx.x;
    const int xcd = d & 7;
    const int tt  = d >> 3;                  // 0..127
    const int bx  = tt & 31;
    const int by  = ((tt >> 5) << 3) | xcd;  // bh, grouped by %8 per XCD
    const int qt  = (31 - bx + by) & 31;
    const int bh  = by;

    const int bb = bh >> 4, h = bh & (NH_ - 1);
    const int q0 = qt * 64;
    const unsigned short* Qh  = Qb   + (size_t)bh * T_ * HD_;
    const unsigned short* Kh  = Kb   + (size_t)bh * T_ * HD_;
    const unsigned short* VTh = Vt_g + (size_t)bh * HD_ * T_;

    const int lrow = t >> 2, lcol = (t & 3) * 16;
    const int qw0 = wid * 16;

    {   // stage Q (already scaled by 1/8)
        const unsigned short* src = &Qh[(size_t)(q0 + lrow) * HD_ + lcol];
        *reinterpret_cast<uint4*>(&Qs[lrow][lcol])     = *reinterpret_cast<const uint4*>(src);
        *reinterpret_cast<uint4*>(&Qs[lrow][lcol + 8]) = *reinterpret_cast<const uint4*>(src + 8);
    }

    float m_run = -1e30f, l_run = 0.f;
    f32x4 yacc[4];
    #pragma unroll
    for (int nt = 0; nt < 4; ++nt) yacc[nt] = (f32x4){0.f, 0.f, 0.f, 0.f};

    // T14 prologue: load tile 0 into regs
    uint4 kv0, kv1, vv0, vv1;
    {
        const unsigned short* ks = &Kh[(size_t)lrow * HD_ + lcol];
        kv0 = *reinterpret_cast<const uint4*>(ks);
        kv1 = *reinterpret_cast<const uint4*>(ks + 8);
        const unsigned short* vs = &VTh[(size_t)lrow * T_ + lcol];
        vv0 = *reinterpret_cast<const uint4*>(vs);
        vv1 = *reinterpret_cast<const uint4*>(vs + 8);
    }

    #pragma unroll 1
    for (int kt = 0; kt <= qt; ++kt) {
        __syncthreads();            // everyone done reading Ks/Vt (prev iter)
        *reinterpret_cast<uint4*>(&Ks[lrow][lcol])     = kv0;
        *reinterpret_cast<uint4*>(&Ks[lrow][lcol + 8]) = kv1;
        *reinterpret_cast<uint4*>(&Vt[lrow][lcol])     = vv0;
        *reinterpret_cast<uint4*>(&Vt[lrow][lcol + 8]) = vv1;
        __syncthreads();            // staging visible (also Q on kt==0)

        if (kt < qt) {              // issue next tile's loads; land during compute
            const int j1 = (kt + 1) * 64;
            const unsigned short* ks = &Kh[(size_t)(j1 + lrow) * HD_ + lcol];
            kv0 = *reinterpret_cast<const uint4*>(ks);
            kv1 = *reinterpret_cast<const uint4*>(ks + 8);
            const unsigned short* vs = &VTh[(size_t)lrow * T_ + j1 + lcol];
            vv0 = *reinterpret_cast<const uint4*>(vs);
            vv1 = *reinterpret_cast<const uint4*>(vs + 8);
        }

        // ---- S^T-tiles = K Q^T : 8 MFMA. lane holds S[q=qw0+c][j=nt*16+4g+r]
        f32x4 sacc[4];
        #pragma unroll
        for (int nt = 0; nt < 4; ++nt) sacc[nt] = (f32x4){0.f, 0.f, 0.f, 0.f};
        __builtin_amdgcn_s_setprio(1);
        #pragma unroll
        for (int kk = 0; kk < 2; ++kk) {
            bf16x8 qf = *reinterpret_cast<const bf16x8*>(&Qs[qw0 + c][kk * 32 + g * 8]);
            #pragma unroll
            for (int nt = 0; nt < 4; ++nt) {
                bf16x8 kf = *reinterpret_cast<const bf16x8*>(&Ks[nt * 16 + c][kk * 32 + g * 8]);
                sacc[nt] = __builtin_amdgcn_mfma_f32_16x16x32_bf16(kf, qf, sacc[nt], 0, 0, 0);
            }
        }
        __builtin_amdgcn_s_setprio(0);

        // ---- online softmax: one q-row per lane ----
        float p[4][4];
        const bool diag = (kt == qt);
        float tmax = -1e30f;
        #pragma unroll
        for (int nt = 0; nt < 4; ++nt)
            #pragma unroll
            for (int r = 0; r < 4; ++r) {
                float s = sacc[nt][r];
                if (diag && (nt * 16 + 4 * g + r > qw0 + c)) s = -1e30f;
                p[nt][r] = s;
                tmax = fmaxf(tmax, s);
            }
        tmax = fmaxf(tmax, __shfl_xor(tmax, 16, 64));
        tmax = fmaxf(tmax, __shfl_xor(tmax, 32, 64));
        const float mnew = fmaxf(m_run, tmax);
        const float sc   = __expf(m_run - mnew);
        m_run = mnew;
        float lsum = 0.f;
        #pragma unroll
        for (int nt = 0; nt < 4; ++nt)
            #pragma unroll
            for (int r = 0; r < 4; ++r) {
                p[nt][r] = __expf(p[nt][r] - mnew);
                lsum += p[nt][r];
            }
        l_run = l_run * sc + lsum;      // per-lane partial (sc row-uniform)

        // rescale factors for yacc layout (row = 4g+r lives at lane 4g+r)
        const int sci = __float_as_int(sc);
        float scr[4];
        #pragma unroll
        for (int r = 0; r < 4; ++r)
            scr[r] = __int_as_float(__builtin_amdgcn_ds_bpermute((4 * g + r) * 4, sci));
        #pragma unroll
        for (int nt = 0; nt < 4; ++nt)
            #pragma unroll
            for (int r = 0; r < 4; ++r) yacc[nt][r] *= scr[r];

        // pack & store P (vectorized 8B: rows q=c, cols j=nt*16+4g..+3)
        #pragma unroll
        for (int nt = 0; nt < 4; ++nt) {
            union { unsigned short s4[4]; uint2 u; } pw;
            #pragma unroll
            for (int r = 0; r < 4; ++r) pw.s4[r] = f2bf(p[nt][r]);
            *reinterpret_cast<uint2*>(&Ps[wid][c][nt * 16 + 4 * g]) = pw.u;
        }

        // ---- y += P V : 8 MFMA (A=P from per-wave Ps, B=V^T from Vt) ----
        __builtin_amdgcn_s_setprio(1);
        #pragma unroll
        for (int kk = 0; kk < 2; ++kk) {
            bf16x8 pa = *reinterpret_cast<const bf16x8*>(&Ps[wid][c][kk * 32 + g * 8]);
            #pragma unroll
            for (int nt = 0; nt < 4; ++nt) {
                bf16x8 vb = *reinterpret_cast<const bf16x8*>(&Vt[nt * 16 + c][kk * 32 + g * 8]);
                yacc[nt] = __builtin_amdgcn_mfma_f32_16x16x32_bf16(pa, vb, yacc[nt], 0, 0, 0);
            }
        }
        __builtin_amdgcn_s_setprio(0);
    }

    // ---- epilogue: finish l (2 shfl), broadcast inv to PV layout, store ----
    float lf = l_run;
    lf += __shfl_xor(lf, 16, 64);
    lf += __shfl_xor(lf, 32, 64);
    const float inv = 1.0f / lf;              // for row q = qw0 + c
    const int ii = __float_as_int(inv);
    float invr[4];
    #pragma unroll
    for (int r = 0; r < 4; ++r)
        invr[r] = __int_as_float(__builtin_amdgcn_ds_bpermute((4 * g + r) * 4, ii));
    #pragma unroll
    for (int r = 0; r < 4; ++r) {
        const size_t row = (size_t)(bb * T_ + q0 + qw0 + 4 * g + r);
        #pragma unroll
        for (int nt = 0; nt < 4; ++nt) {
            const int col = h * HD_ + 16 * nt + c;
            Yu[row * C_ + col] = f2bf(yacc[nt][r] * invr[r]);
        }
    }
}

extern "C" void kernel_launch(void* const* d_in, const int* in_sizes, int n_in,
                              void* d_out, int out_size, void* d_ws, size_t ws_size,
                              hipStream_t stream) {
    const float* x      = (const float*)d_in[0];
    const float* w_qkv  = (const float*)d_in[1];
    const float* w_proj = (const float*)d_in[2];
    float* out = (float*)d_out;

    const size_t HELEMS = (size_t)B_ * NH_ * T_ * HD_;   // 4,194,304
    unsigned short* Qb  = (unsigned short*)d_ws;
    unsigned short* Kb  = Qb + HELEMS;
    unsigned short* Vb  = Kb + HELEMS;        // transposed layout [bh][d][T]
    unsigned short* Xb  = Vb + HELEMS;        // aliased: Yb reuses Xb after qkv
    unsigned short* Yb  = Xb;
    unsigned short* Wqt = Xb + HELEMS;        // 3072x1024
    unsigned short* Wpt = Wqt;                // aliased: cast after qkv_gemm

    const int NX = B_ * T_ * C_;              // 4,194,304
    cast_bf16<<<NX / (256 * 8), 256, 0, stream>>>(x, Xb, NX);
    transpose_cast<<<dim3(48, 16), 256, 0, stream>>>(w_qkv, Wqt, 3 * C_, C_);
    qkv_gemm_mfma<<<dim3(24, 32), 256, 0, stream>>>(Xb, Wqt, Qb, Kb, Vb);
    transpose_cast<<<dim3(16, 16), 256, 0, stream>>>(w_proj, Wpt, C_, C_);
    attn_mfma<<<1024, 256, 0, stream>>>(Qb, Kb, Vb, Yb);
    proj_gemm_mfma<<<dim3(8, 32), 256, 0, stream>>>(Yb, Wpt, out);
}